// Round 15
// baseline (189.110 us; speedup 1.0000x reference)
//
#include <hip/hip_runtime.h>
#include <hip/hip_bf16.h>

#define V_NODES 100000
#define DIM 128
#define BATCH 16384
#define SAMP 64
#define NEDGE 640000
#define NSAMP (BATCH * SAMP)

// bf16 helpers: raw-bit unpack (exact) and RNE pack
__device__ __forceinline__ float bl(unsigned u) { return __uint_as_float(u << 16); }
__device__ __forceinline__ float bh(unsigned u) { return __uint_as_float(u & 0xffff0000u); }
__device__ __forceinline__ unsigned short f2bf(float x) {
    unsigned u = __float_as_uint(x);
    return (unsigned short)((u + 0x7fffu + ((u >> 16) & 1u)) >> 16);
}

typedef __attribute__((ext_vector_type(8))) short bf16x8;
typedef __attribute__((ext_vector_type(4))) float f32x4;

// ---------- K0a: zero cnt (runtime fillBuffer measured 43.8us!) ----------
__global__ void k_zero(int4* __restrict__ p, int n4) {
    int i = blockIdx.x * blockDim.x + threadIdx.x;
    if (i < n4) p[i] = make_int4(0, 0, 0, 0);
}

// ---------- K0b: one-time W^T -> bf16 global (64 KB read, 32 KB write) ----------
__global__ void k_wcvt(const float* __restrict__ W, unsigned short* __restrict__ wt_bf) {
    int g = blockIdx.x * blockDim.x + threadIdx.x;   // 16 blocks x 256
    int n = g & 127;
    int k4 = (g >> 7) << 2;
    ushort4 o;
    o.x = f2bf(W[(k4 + 0) * 128 + n]);
    o.y = f2bf(W[(k4 + 1) * 128 + n]);
    o.z = f2bf(W[(k4 + 2) * 128 + n]);
    o.w = f2bf(W[(k4 + 3) * 128 + n]);
    *(ushort4*)(wt_bf + n * 128 + k4) = o;
}

// ---------- K1: histogram of edge destinations (in-degree) ----------
__global__ void k_count(const int* __restrict__ key, int* __restrict__ cnt, int E) {
    int e = blockIdx.x * blockDim.x + threadIdx.x;
    if (e < E) atomicAdd(&cnt[key[e]], 1);
}

// ---------- K2a: per-1024-chunk sums ----------
__global__ void k_bsum(const int* __restrict__ cnt, int* __restrict__ bsum, int V) {
    __shared__ int red[4];
    int b = blockIdx.x, t = threadIdx.x;
    int s = 0;
    int base = b * 1024;
    for (int i = 0; i < 4; ++i) {
        int idx = base + i * 256 + t;
        if (idx < V) s += cnt[idx];
    }
    for (int m = 32; m >= 1; m >>= 1) s += __shfl_xor(s, m, 64);
    int lane = t & 63, wid = t >> 6;
    if (lane == 0) red[wid] = s;
    __syncthreads();
    if (t == 0) bsum[b] = red[0] + red[1] + red[2] + red[3];
}

// ---------- K2b: single-wave shuffle scan of chunk sums ----------
__global__ void k_bscan(const int* __restrict__ bsum, int* __restrict__ boff, int nb) {
    int l = threadIdx.x;            // 64 threads, 2 elements per lane
    int i0 = 2 * l, i1 = 2 * l + 1;
    int v0 = (i0 < nb) ? bsum[i0] : 0;
    int v1 = (i1 < nb) ? bsum[i1] : 0;
    int s = v0 + v1;
    int x = s;
    for (int off = 1; off < 64; off <<= 1) {
        int n = __shfl_up(x, off, 64);
        if (l >= off) x += n;
    }
    int excl = x - s;
    if (i0 < nb) boff[i0] = excl;
    if (i1 < nb) boff[i1] = excl + v0;
}

// ---------- K2c: exclusive CSR offsets + dinv + absolute cursor init ----------
__global__ void k_offs(const int* __restrict__ cnt, const int* __restrict__ boff,
                       int* __restrict__ offs, float* __restrict__ dinv,
                       int* __restrict__ cursor, int V) {
    __shared__ int wsum[4];
    int b = blockIdx.x, t = threadIdx.x;
    int lane = t & 63, wid = t >> 6;
    int base = b * 1024 + t * 4;
    int c[4];
    for (int j = 0; j < 4; ++j) {
        int idx = base + j;
        c[j] = (idx < V) ? cnt[idx] : 0;
    }
    int tot = c[0] + c[1] + c[2] + c[3];
    int x = tot;
    for (int off = 1; off < 64; off <<= 1) {
        int n = __shfl_up(x, off, 64);
        if (lane >= off) x += n;
    }
    int lex = x - tot;
    if (lane == 63) wsum[wid] = x;
    __syncthreads();
    int wpre = 0;
    for (int w = 0; w < wid; ++w) wpre += wsum[w];
    int o = boff[b] + wpre + lex;
    int pre = 0;
    for (int j = 0; j < 4; ++j) {
        int idx = base + j;
        if (idx < V) {
            int o0 = o + pre;
            offs[idx] = o0;
            cursor[idx] = o0;                        // absolute cursor
            dinv[idx] = 1.0f / sqrtf((float)(c[j] + 1));
        }
        pre += c[j];
    }
}

// ---------- K3: fill edge CSR (absolute atomic cursors) ----------
__global__ void k_fill(const int* __restrict__ src, const int* __restrict__ dst,
                       int* __restrict__ cursor, int* __restrict__ csr, int E) {
    int e = blockIdx.x * blockDim.x + threadIdx.x;
    if (e < E) {
        int pos = atomicAdd(&cursor[dst[e]], 1);
        csr[pos] = src[e];
    }
}

// ---------- K4: MFMA GEMM  h_bf = bf16(bf16(emb) @ bf16(W)) ----------
// 64 rows x 128 cols per block. A direct from global (coalesced fp32, reg-cvt).
// B direct from global wt_bf: the whole W^T is 32 KB -> L1-resident per CU, so
// NO LDS staging (R14 staged it per block = 50 MB of wasted traffic + barriers).
// Only LDS use: 16 KB swizzled D-staging for coalesced bf16 output.
__global__ __launch_bounds__(256) void k_hgemm(const float* __restrict__ emb,
                      unsigned short* __restrict__ h_bf,
                      const unsigned short* __restrict__ wt_bf, int V) {
    __shared__ unsigned short DsL[64 * 128];   // 16 KB
    int t = threadIdx.x;
    int rowbase = blockIdx.x * 64;
    int wid = t >> 6, lane = t & 63;
    int r16  = lane & 15;
    int kgrp = lane >> 4;
    // A fragment: direct global loads (8 x float4, independent)
    int grow = rowbase + wid * 16 + r16;
    const float* arow = emb + (size_t)grow * 128 + kgrp * 8;
    bool ok = (grow < V);
    float4 af[8];
    #pragma unroll
    for (int ks = 0; ks < 4; ++ks) {
        af[2 * ks]     = ok ? *(const float4*)(arow + ks * 32)     : make_float4(0.f, 0.f, 0.f, 0.f);
        af[2 * ks + 1] = ok ? *(const float4*)(arow + ks * 32 + 4) : make_float4(0.f, 0.f, 0.f, 0.f);
    }
    f32x4 acc[8] = {};
    #pragma unroll
    for (int ks = 0; ks < 4; ++ks) {
        float4 a0 = af[2 * ks], a1 = af[2 * ks + 1];
        bf16x8 a;
        a[0] = (short)f2bf(a0.x); a[1] = (short)f2bf(a0.y);
        a[2] = (short)f2bf(a0.z); a[3] = (short)f2bf(a0.w);
        a[4] = (short)f2bf(a1.x); a[5] = (short)f2bf(a1.y);
        a[6] = (short)f2bf(a1.z); a[7] = (short)f2bf(a1.w);
        int kc = ks * 32 + kgrp * 8;
        #pragma unroll
        for (int n = 0; n < 8; ++n) {
            bf16x8 b = *(const bf16x8*)(wt_bf + (n * 16 + r16) * 128 + kc);  // L1-hot
            acc[n] = __builtin_amdgcn_mfma_f32_16x16x32_bf16(a, b, acc[n], 0, 0, 0);
        }
    }
    // D -> swizzled LDS -> coalesced global
    #pragma unroll
    for (int n = 0; n < 8; ++n) {
        #pragma unroll
        for (int r = 0; r < 4; ++r) {
            int drow = wid * 16 + kgrp * 4 + r;
            int dcol = n * 16 + r16;
            DsL[drow * 128 + (dcol ^ ((drow & 7) << 3))] = f2bf(acc[n][r]);
        }
    }
    __syncthreads();
    for (int i = 0; i < 4; ++i) {       // 1024 uint4s: 64 rows x 16 blocks
        int j = t + i * 256;
        int r = j >> 4, c8 = (j & 15) << 3;
        uint4 v = *(const uint4*)&DsL[r * 128 + (c8 ^ ((r & 7) << 3))];
        int gr = rowbase + r;
        if (gr < V) *(uint4*)(h_bf + (size_t)gr * 128 + c8) = v;
    }
}

// ---------- K5: aggregate h, + bias, write bf16 nodes ----------
// TWO nodes per wave, interleaved x2 -> 4 independent gathers in flight even at
// deg ~3-6 (the x4 single-node unroll only covered deg>=4; mean deg = 6.4).
__global__ __launch_bounds__(256) void k_agg(const unsigned short* __restrict__ h_bf,
                     const int* __restrict__ offs, const int* __restrict__ cnt,
                     const int* __restrict__ csr, const float* __restrict__ dinv,
                     const float* __restrict__ bias,
                     unsigned* __restrict__ nodes_h, int V) {
    int wv = threadIdx.x >> 6;
    int lane = threadIdx.x & 63;
    int vA = blockIdx.x * 8 + wv * 2;
    int vB = vA + 1;
    if (vA >= V) return;
    bool hasB = (vB < V);
    float dvA = dinv[vA];
    float dvB = hasB ? dinv[vB] : 0.f;
    int begA = offs[vA], numA = cnt[vA];
    int begB = hasB ? offs[vB] : 0, numB = hasB ? cnt[vB] : 0;
    int nidA = 0, nidB = 0; float nwA = 0.f, nwB = 0.f;
    if (lane < numA) { nidA = csr[begA + lane]; nwA = dinv[nidA]; }
    if (lane < numB) { nidB = csr[begB + lane]; nwB = dinv[nidB]; }
    unsigned u0A = ((const unsigned*)(h_bf + (size_t)vA * DIM))[lane];
    unsigned u0B = hasB ? ((const unsigned*)(h_bf + (size_t)vB * DIM))[lane] : 0u;
    float2 bv = ((const float2*)bias)[lane];
    float axA = bv.x + dvA * dvA * bl(u0A), ayA = bv.y + dvA * dvA * bh(u0A);
    float axB = bv.x + dvB * dvB * bl(u0B), ayB = bv.y + dvB * dvB * bh(u0B);
    float cxA = 0.f, cyA = 0.f, cxB = 0.f, cyB = 0.f;
    int nA = min(numA, 64), nB = min(numB, 64);
    int m = min(nA, nB);
    int i = 0;
    for (; i + 2 <= m; i += 2) {            // interleaved: 4 loads in flight
        int sA0 = __shfl(nidA, i, 64),     sB0 = __shfl(nidB, i, 64);
        int sA1 = __shfl(nidA, i + 1, 64), sB1 = __shfl(nidB, i + 1, 64);
        float wA0 = dvA * __shfl(nwA, i, 64),     wB0 = dvB * __shfl(nwB, i, 64);
        float wA1 = dvA * __shfl(nwA, i + 1, 64), wB1 = dvB * __shfl(nwB, i + 1, 64);
        unsigned eA0 = ((const unsigned*)(h_bf + (size_t)sA0 * DIM))[lane];
        unsigned eB0 = ((const unsigned*)(h_bf + (size_t)sB0 * DIM))[lane];
        unsigned eA1 = ((const unsigned*)(h_bf + (size_t)sA1 * DIM))[lane];
        unsigned eB1 = ((const unsigned*)(h_bf + (size_t)sB1 * DIM))[lane];
        axA += wA0 * bl(eA0); ayA += wA0 * bh(eA0);
        axB += wB0 * bl(eB0); ayB += wB0 * bh(eB0);
        cxA += wA1 * bl(eA1); cyA += wA1 * bh(eA1);
        cxB += wB1 * bl(eB1); cyB += wB1 * bh(eB1);
    }
    // tail A (x2 unrolled, then scalar)
    int ia = i;
    for (; ia + 2 <= nA; ia += 2) {
        int s0 = __shfl(nidA, ia, 64), s1 = __shfl(nidA, ia + 1, 64);
        float w0 = dvA * __shfl(nwA, ia, 64), w1 = dvA * __shfl(nwA, ia + 1, 64);
        unsigned e0 = ((const unsigned*)(h_bf + (size_t)s0 * DIM))[lane];
        unsigned e1 = ((const unsigned*)(h_bf + (size_t)s1 * DIM))[lane];
        axA += w0 * bl(e0); ayA += w0 * bh(e0);
        cxA += w1 * bl(e1); cyA += w1 * bh(e1);
    }
    for (; ia < nA; ++ia) {
        int s = __shfl(nidA, ia, 64);
        float w = dvA * __shfl(nwA, ia, 64);
        unsigned u = ((const unsigned*)(h_bf + (size_t)s * DIM))[lane];
        axA += w * bl(u); ayA += w * bh(u);
    }
    // tail B
    int ib = i;
    for (; ib + 2 <= nB; ib += 2) {
        int s0 = __shfl(nidB, ib, 64), s1 = __shfl(nidB, ib + 1, 64);
        float w0 = dvB * __shfl(nwB, ib, 64), w1 = dvB * __shfl(nwB, ib + 1, 64);
        unsigned e0 = ((const unsigned*)(h_bf + (size_t)s0 * DIM))[lane];
        unsigned e1 = ((const unsigned*)(h_bf + (size_t)s1 * DIM))[lane];
        axB += w0 * bl(e0); ayB += w0 * bh(e0);
        cxB += w1 * bl(e1); cyB += w1 * bh(e1);
    }
    for (; ib < nB; ++ib) {
        int s = __shfl(nidB, ib, 64);
        float w = dvB * __shfl(nwB, ib, 64);
        unsigned u = ((const unsigned*)(h_bf + (size_t)s * DIM))[lane];
        axB += w * bl(u); ayB += w * bh(u);
    }
    // cold fallback deg>64 (deg>64 ~ impossible, Poisson(6.4))
    for (int k = 64; k < numA; ++k) {
        int s = csr[begA + k];
        float w = dvA * dinv[s];
        unsigned u = ((const unsigned*)(h_bf + (size_t)s * DIM))[lane];
        axA += w * bl(u); ayA += w * bh(u);
    }
    for (int k = 64; k < numB; ++k) {
        int s = csr[begB + k];
        float w = dvB * dinv[s];
        unsigned u = ((const unsigned*)(h_bf + (size_t)s * DIM))[lane];
        axB += w * bl(u); ayB += w * bh(u);
    }
    axA += cxA; ayA += cyA;
    nodes_h[(size_t)vA * (DIM / 2) + lane] =
        (unsigned)f2bf(axA) | ((unsigned)f2bf(ayA) << 16);
    if (hasB) {
        axB += cxB; ayB += cyB;
        nodes_h[(size_t)vB * (DIM / 2) + lane] =
            (unsigned)f2bf(axB) | ((unsigned)f2bf(ayB) << 16);
    }
}

// ---------- K6: scores[b,s] = dot(nodes[items[b]], nodes[samples[b,s]]) ----------
// R7 shape (best measured): 256-thread block per item; 4 threads per sample.
__global__ __launch_bounds__(256) void k_score(const unsigned short* __restrict__ nodes_h,
                      const int* __restrict__ items, const int* __restrict__ samples,
                      float* __restrict__ out) {
    int b = blockIdx.x;
    int t = threadIdx.x;
    int q = t & 3;
    int sidx = t >> 2;
    int item = items[b];
    const uint4* irow = (const uint4*)(nodes_h + (size_t)item * DIM) + q * 4;
    uint4 a[4];
    #pragma unroll
    for (int c = 0; c < 4; ++c) a[c] = irow[c];

    int j = samples[b * SAMP + sidx];
    const uint4* srow = (const uint4*)(nodes_h + (size_t)j * DIM) + q * 4;
    uint4 s4[4];
    #pragma unroll
    for (int c = 0; c < 4; ++c) s4[c] = srow[c];

    float p = 0.f;
    #pragma unroll
    for (int c = 0; c < 4; ++c) {
        uint4 av = a[c], sv = s4[c];
        p += bl(av.x) * bl(sv.x) + bh(av.x) * bh(sv.x);
        p += bl(av.y) * bl(sv.y) + bh(av.y) * bh(sv.y);
        p += bl(av.z) * bl(sv.z) + bh(av.z) * bh(sv.z);
        p += bl(av.w) * bl(sv.w) + bh(av.w) * bh(sv.w);
    }
    p += __shfl_xor(p, 1, 64);
    p += __shfl_xor(p, 2, 64);
    if (q == 0) out[b * SAMP + sidx] = p;
}

extern "C" void kernel_launch(void* const* d_in, const int* in_sizes, int n_in,
                              void* d_out, int out_size, void* d_ws, size_t ws_size,
                              hipStream_t stream) {
    const int*   items   = (const int*)d_in[0];
    const int*   samples = (const int*)d_in[1];
    const int*   edges   = (const int*)d_in[2];
    const float* emb     = (const float*)d_in[3];
    const float* W       = (const float*)d_in[4];
    const float* bias    = (const float*)d_in[5];
    float* out = (float*)d_out;

    char* ws = (char*)d_ws;
    int*   cnt    = (int*)(ws + 0);                        // V ints (400 KB)
    int*   cursor = (int*)(ws + (512 << 10));              // V ints
    float* dinv   = (float*)(ws + (1 << 20));              // V floats
    int*   offs   = (int*)(ws + 3 * (512 << 10));          // V ints
    int*   bsum   = (int*)(ws + (2 << 20));                // 98 ints
    int*   boff   = (int*)(ws + (2 << 20) + (4 << 10));    // 98 ints
    unsigned short* wt_bf = (unsigned short*)(ws + (3 << 20));     // 128x128 bf16 (32 KB)
    int*   csr    = (int*)(ws + (4 << 20));                // E ints (2.56 MB)
    unsigned short* h_bf    = (unsigned short*)(ws + (8 << 20));   // V*DIM bf16 (25.6 MB)
    unsigned*       nodes_h = (unsigned*)(ws + (34 << 20));        // V*DIM bf16 (25.6 MB)

    const int* esrc = edges;
    const int* edst = edges + NEDGE;

    int nb = (V_NODES + 1023) / 1024;   // 98
    k_zero <<<98, 256, 0, stream>>>((int4*)cnt, V_NODES / 4);
    k_wcvt <<<16, 256, 0, stream>>>(W, wt_bf);
    // edge CSR: separate parallel kernels (fusion regressed: R9 coop, R11 scanoffs)
    k_count<<<(NEDGE + 255) / 256, 256, 0, stream>>>(edst, cnt, NEDGE);
    k_bsum <<<nb, 256, 0, stream>>>(cnt, bsum, V_NODES);
    k_bscan<<<1, 64, 0, stream>>>(bsum, boff, nb);
    k_offs <<<nb, 256, 0, stream>>>(cnt, boff, offs, dinv, cursor, V_NODES);
    k_fill <<<(NEDGE + 255) / 256, 256, 0, stream>>>(esrc, edst, cursor, csr, NEDGE);
    // GCN: MFMA GEMM first (reference order), then aggregate
    k_hgemm<<<(V_NODES + 63) / 64, 256, 0, stream>>>(emb, h_bf, wt_bf, V_NODES);
    k_agg  <<<(V_NODES + 7) / 8, 256, 0, stream>>>(h_bf, offs, cnt, csr, dinv, bias, nodes_h, V_NODES);
    // scoring
    k_score<<<BATCH, 256, 0, stream>>>((const unsigned short*)nodes_h, items, samples, out);
}

// Round 16
// 167.220 us; speedup vs baseline: 1.1309x; 1.1309x over previous
//
#include <hip/hip_runtime.h>
#include <hip/hip_bf16.h>

#define V_NODES 100000
#define DIM 128
#define BATCH 16384
#define SAMP 64
#define NEDGE 640000
#define NSAMP (BATCH * SAMP)

// bf16 helpers: raw-bit unpack (exact) and RNE pack
__device__ __forceinline__ float bl(unsigned u) { return __uint_as_float(u << 16); }
__device__ __forceinline__ float bh(unsigned u) { return __uint_as_float(u & 0xffff0000u); }
__device__ __forceinline__ unsigned short f2bf(float x) {
    unsigned u = __float_as_uint(x);
    return (unsigned short)((u + 0x7fffu + ((u >> 16) & 1u)) >> 16);
}

typedef __attribute__((ext_vector_type(8))) short bf16x8;
typedef __attribute__((ext_vector_type(4))) float f32x4;

// ---------- K0a: zero cnt (runtime fillBuffer measured 43.8us!) ----------
__global__ void k_zero(int4* __restrict__ p, int n4) {
    int i = blockIdx.x * blockDim.x + threadIdx.x;
    if (i < n4) p[i] = make_int4(0, 0, 0, 0);
}

// ---------- K0b: one-time W^T -> bf16 global (64 KB read, 32 KB write) ----------
__global__ void k_wcvt(const float* __restrict__ W, unsigned short* __restrict__ wt_bf) {
    int g = blockIdx.x * blockDim.x + threadIdx.x;   // 16 blocks x 256
    int n = g & 127;
    int k4 = (g >> 7) << 2;
    ushort4 o;
    o.x = f2bf(W[(k4 + 0) * 128 + n]);
    o.y = f2bf(W[(k4 + 1) * 128 + n]);
    o.z = f2bf(W[(k4 + 2) * 128 + n]);
    o.w = f2bf(W[(k4 + 3) * 128 + n]);
    *(ushort4*)(wt_bf + n * 128 + k4) = o;
}

// ---------- K1: histogram of edge destinations (in-degree) ----------
__global__ void k_count(const int* __restrict__ key, int* __restrict__ cnt, int E) {
    int e = blockIdx.x * blockDim.x + threadIdx.x;
    if (e < E) atomicAdd(&cnt[key[e]], 1);
}

// ---------- K2a: per-1024-chunk sums ----------
__global__ void k_bsum(const int* __restrict__ cnt, int* __restrict__ bsum, int V) {
    __shared__ int red[4];
    int b = blockIdx.x, t = threadIdx.x;
    int s = 0;
    int base = b * 1024;
    for (int i = 0; i < 4; ++i) {
        int idx = base + i * 256 + t;
        if (idx < V) s += cnt[idx];
    }
    for (int m = 32; m >= 1; m >>= 1) s += __shfl_xor(s, m, 64);
    int lane = t & 63, wid = t >> 6;
    if (lane == 0) red[wid] = s;
    __syncthreads();
    if (t == 0) bsum[b] = red[0] + red[1] + red[2] + red[3];
}

// ---------- K2b: single-wave shuffle scan of chunk sums ----------
__global__ void k_bscan(const int* __restrict__ bsum, int* __restrict__ boff, int nb) {
    int l = threadIdx.x;            // 64 threads, 2 elements per lane
    int i0 = 2 * l, i1 = 2 * l + 1;
    int v0 = (i0 < nb) ? bsum[i0] : 0;
    int v1 = (i1 < nb) ? bsum[i1] : 0;
    int s = v0 + v1;
    int x = s;
    for (int off = 1; off < 64; off <<= 1) {
        int n = __shfl_up(x, off, 64);
        if (l >= off) x += n;
    }
    int excl = x - s;
    if (i0 < nb) boff[i0] = excl;
    if (i1 < nb) boff[i1] = excl + v0;
}

// ---------- K2c: exclusive CSR offsets + dinv + absolute cursor init ----------
__global__ void k_offs(const int* __restrict__ cnt, const int* __restrict__ boff,
                       int* __restrict__ offs, float* __restrict__ dinv,
                       int* __restrict__ cursor, int V) {
    __shared__ int wsum[4];
    int b = blockIdx.x, t = threadIdx.x;
    int lane = t & 63, wid = t >> 6;
    int base = b * 1024 + t * 4;
    int c[4];
    for (int j = 0; j < 4; ++j) {
        int idx = base + j;
        c[j] = (idx < V) ? cnt[idx] : 0;
    }
    int tot = c[0] + c[1] + c[2] + c[3];
    int x = tot;
    for (int off = 1; off < 64; off <<= 1) {
        int n = __shfl_up(x, off, 64);
        if (lane >= off) x += n;
    }
    int lex = x - tot;
    if (lane == 63) wsum[wid] = x;
    __syncthreads();
    int wpre = 0;
    for (int w = 0; w < wid; ++w) wpre += wsum[w];
    int o = boff[b] + wpre + lex;
    int pre = 0;
    for (int j = 0; j < 4; ++j) {
        int idx = base + j;
        if (idx < V) {
            int o0 = o + pre;
            offs[idx] = o0;
            cursor[idx] = o0;                        // absolute cursor
            dinv[idx] = 1.0f / sqrtf((float)(c[j] + 1));
        }
        pre += c[j];
    }
}

// ---------- K3: fill edge CSR (absolute atomic cursors) ----------
__global__ void k_fill(const int* __restrict__ src, const int* __restrict__ dst,
                       int* __restrict__ cursor, int* __restrict__ csr, int E) {
    int e = blockIdx.x * blockDim.x + threadIdx.x;
    if (e < E) {
        int pos = atomicAdd(&cursor[dst[e]], 1);
        csr[pos] = src[e];
    }
}

// ---------- K4: MFMA GEMM  h_bf = bf16(bf16(emb) @ bf16(W)) ----------
// 128 rows x 128 cols per block, 512 threads (8 waves x 16 rows). W^T staged
// once per block in a 32 KB XOR-swizzled LDS tile (R14-proven: conflicts=0);
// R15's L1-direct B read was a 16-row gather and regressed — LDS restored.
// A direct from global (coalesced fp32, reg-cvt). Dead W tile reused for
// swizzled D staging (exactly 128x128 shorts).
__global__ __launch_bounds__(512) void k_hgemm(const float* __restrict__ emb,
                      unsigned short* __restrict__ h_bf,
                      const unsigned short* __restrict__ wt_bf, int V) {
    __shared__ unsigned short WtL[128 * 128];   // 32 KB
    int t = threadIdx.x;
    int rowbase = blockIdx.x * 128;
    // stage swizzled W^T: 2048 uint4s = 128 rows x 16 8-short blocks; 4/thread
    for (int i = 0; i < 4; ++i) {
        int j = t + i * 512;
        int n = j >> 4, c8 = (j & 15) << 3;
        uint4 v = *(const uint4*)(wt_bf + n * 128 + c8);
        *(uint4*)&WtL[n * 128 + (c8 ^ ((n & 7) << 3))] = v;
    }
    int wid = t >> 6, lane = t & 63;   // 8 waves
    int r16  = lane & 15;
    int kgrp = lane >> 4;
    // A fragment: direct global loads (8 x float4, independent)
    int grow = rowbase + wid * 16 + r16;
    const float* arow = emb + (size_t)grow * 128 + kgrp * 8;
    bool ok = (grow < V);
    float4 af[8];
    #pragma unroll
    for (int ks = 0; ks < 4; ++ks) {
        af[2 * ks]     = ok ? *(const float4*)(arow + ks * 32)     : make_float4(0.f, 0.f, 0.f, 0.f);
        af[2 * ks + 1] = ok ? *(const float4*)(arow + ks * 32 + 4) : make_float4(0.f, 0.f, 0.f, 0.f);
    }
    __syncthreads();
    f32x4 acc[8] = {};
    #pragma unroll
    for (int ks = 0; ks < 4; ++ks) {
        float4 a0 = af[2 * ks], a1 = af[2 * ks + 1];
        bf16x8 a;
        a[0] = (short)f2bf(a0.x); a[1] = (short)f2bf(a0.y);
        a[2] = (short)f2bf(a0.z); a[3] = (short)f2bf(a0.w);
        a[4] = (short)f2bf(a1.x); a[5] = (short)f2bf(a1.y);
        a[6] = (short)f2bf(a1.z); a[7] = (short)f2bf(a1.w);
        int kc = ks * 32 + kgrp * 8;
        #pragma unroll
        for (int n = 0; n < 8; ++n) {
            int wr = n * 16 + r16;
            bf16x8 b = *(const bf16x8*)&WtL[wr * 128 + (kc ^ ((wr & 7) << 3))];
            acc[n] = __builtin_amdgcn_mfma_f32_16x16x32_bf16(a, b, acc[n], 0, 0, 0);
        }
    }
    __syncthreads();   // WtL dead; reuse for D staging (128 rows x 128 cols)
    #pragma unroll
    for (int n = 0; n < 8; ++n) {
        #pragma unroll
        for (int r = 0; r < 4; ++r) {
            int drow = wid * 16 + kgrp * 4 + r;
            int dcol = n * 16 + r16;
            WtL[drow * 128 + (dcol ^ ((drow & 7) << 3))] = f2bf(acc[n][r]);
        }
    }
    __syncthreads();
    for (int i = 0; i < 4; ++i) {       // 2048 uint4s: 128 rows x 16 blocks
        int j = t + i * 512;
        int r = j >> 4, c8 = (j & 15) << 3;
        uint4 v = *(const uint4*)&WtL[r * 128 + (c8 ^ ((r & 7) << 3))];
        int gr = rowbase + r;
        if (gr < V) *(uint4*)(h_bf + (size_t)gr * 128 + c8) = v;
    }
}

// ---------- K5: aggregate h, + bias, write bf16 nodes ----------
// TWO nodes per wave, interleaved x2 -> 4 independent gathers in flight even at
// deg ~3-6 (mean deg = 6.4).
__global__ __launch_bounds__(256) void k_agg(const unsigned short* __restrict__ h_bf,
                     const int* __restrict__ offs, const int* __restrict__ cnt,
                     const int* __restrict__ csr, const float* __restrict__ dinv,
                     const float* __restrict__ bias,
                     unsigned* __restrict__ nodes_h, int V) {
    int wv = threadIdx.x >> 6;
    int lane = threadIdx.x & 63;
    int vA = blockIdx.x * 8 + wv * 2;
    int vB = vA + 1;
    if (vA >= V) return;
    bool hasB = (vB < V);
    float dvA = dinv[vA];
    float dvB = hasB ? dinv[vB] : 0.f;
    int begA = offs[vA], numA = cnt[vA];
    int begB = hasB ? offs[vB] : 0, numB = hasB ? cnt[vB] : 0;
    int nidA = 0, nidB = 0; float nwA = 0.f, nwB = 0.f;
    if (lane < numA) { nidA = csr[begA + lane]; nwA = dinv[nidA]; }
    if (lane < numB) { nidB = csr[begB + lane]; nwB = dinv[nidB]; }
    unsigned u0A = ((const unsigned*)(h_bf + (size_t)vA * DIM))[lane];
    unsigned u0B = hasB ? ((const unsigned*)(h_bf + (size_t)vB * DIM))[lane] : 0u;
    float2 bv = ((const float2*)bias)[lane];
    float axA = bv.x + dvA * dvA * bl(u0A), ayA = bv.y + dvA * dvA * bh(u0A);
    float axB = bv.x + dvB * dvB * bl(u0B), ayB = bv.y + dvB * dvB * bh(u0B);
    float cxA = 0.f, cyA = 0.f, cxB = 0.f, cyB = 0.f;
    int nA = min(numA, 64), nB = min(numB, 64);
    int m = min(nA, nB);
    int i = 0;
    for (; i + 2 <= m; i += 2) {            // interleaved: 4 loads in flight
        int sA0 = __shfl(nidA, i, 64),     sB0 = __shfl(nidB, i, 64);
        int sA1 = __shfl(nidA, i + 1, 64), sB1 = __shfl(nidB, i + 1, 64);
        float wA0 = dvA * __shfl(nwA, i, 64),     wB0 = dvB * __shfl(nwB, i, 64);
        float wA1 = dvA * __shfl(nwA, i + 1, 64), wB1 = dvB * __shfl(nwB, i + 1, 64);
        unsigned eA0 = ((const unsigned*)(h_bf + (size_t)sA0 * DIM))[lane];
        unsigned eB0 = ((const unsigned*)(h_bf + (size_t)sB0 * DIM))[lane];
        unsigned eA1 = ((const unsigned*)(h_bf + (size_t)sA1 * DIM))[lane];
        unsigned eB1 = ((const unsigned*)(h_bf + (size_t)sB1 * DIM))[lane];
        axA += wA0 * bl(eA0); ayA += wA0 * bh(eA0);
        axB += wB0 * bl(eB0); ayB += wB0 * bh(eB0);
        cxA += wA1 * bl(eA1); cyA += wA1 * bh(eA1);
        cxB += wB1 * bl(eB1); cyB += wB1 * bh(eB1);
    }
    // tail A (x2 unrolled, then scalar)
    int ia = i;
    for (; ia + 2 <= nA; ia += 2) {
        int s0 = __shfl(nidA, ia, 64), s1 = __shfl(nidA, ia + 1, 64);
        float w0 = dvA * __shfl(nwA, ia, 64), w1 = dvA * __shfl(nwA, ia + 1, 64);
        unsigned e0 = ((const unsigned*)(h_bf + (size_t)s0 * DIM))[lane];
        unsigned e1 = ((const unsigned*)(h_bf + (size_t)s1 * DIM))[lane];
        axA += w0 * bl(e0); ayA += w0 * bh(e0);
        cxA += w1 * bl(e1); cyA += w1 * bh(e1);
    }
    for (; ia < nA; ++ia) {
        int s = __shfl(nidA, ia, 64);
        float w = dvA * __shfl(nwA, ia, 64);
        unsigned u = ((const unsigned*)(h_bf + (size_t)s * DIM))[lane];
        axA += w * bl(u); ayA += w * bh(u);
    }
    // tail B
    int ib = i;
    for (; ib + 2 <= nB; ib += 2) {
        int s0 = __shfl(nidB, ib, 64), s1 = __shfl(nidB, ib + 1, 64);
        float w0 = dvB * __shfl(nwB, ib, 64), w1 = dvB * __shfl(nwB, ib + 1, 64);
        unsigned e0 = ((const unsigned*)(h_bf + (size_t)s0 * DIM))[lane];
        unsigned e1 = ((const unsigned*)(h_bf + (size_t)s1 * DIM))[lane];
        axB += w0 * bl(e0); ayB += w0 * bh(e0);
        cxB += w1 * bl(e1); cyB += w1 * bh(e1);
    }
    for (; ib < nB; ++ib) {
        int s = __shfl(nidB, ib, 64);
        float w = dvB * __shfl(nwB, ib, 64);
        unsigned u = ((const unsigned*)(h_bf + (size_t)s * DIM))[lane];
        axB += w * bl(u); ayB += w * bh(u);
    }
    // cold fallback deg>64 (deg>64 ~ impossible, Poisson(6.4))
    for (int k = 64; k < numA; ++k) {
        int s = csr[begA + k];
        float w = dvA * dinv[s];
        unsigned u = ((const unsigned*)(h_bf + (size_t)s * DIM))[lane];
        axA += w * bl(u); ayA += w * bh(u);
    }
    for (int k = 64; k < numB; ++k) {
        int s = csr[begB + k];
        float w = dvB * dinv[s];
        unsigned u = ((const unsigned*)(h_bf + (size_t)s * DIM))[lane];
        axB += w * bl(u); ayB += w * bh(u);
    }
    axA += cxA; ayA += cyA;
    nodes_h[(size_t)vA * (DIM / 2) + lane] =
        (unsigned)f2bf(axA) | ((unsigned)f2bf(ayA) << 16);
    if (hasB) {
        axB += cxB; ayB += cyB;
        nodes_h[(size_t)vB * (DIM / 2) + lane] =
            (unsigned)f2bf(axB) | ((unsigned)f2bf(ayB) << 16);
    }
}

// ---------- K6: scores[b,s] = dot(nodes[items[b]], nodes[samples[b,s]]) ----------
// R7 shape (best measured): 256-thread block per item; 4 threads per sample.
__global__ __launch_bounds__(256) void k_score(const unsigned short* __restrict__ nodes_h,
                      const int* __restrict__ items, const int* __restrict__ samples,
                      float* __restrict__ out) {
    int b = blockIdx.x;
    int t = threadIdx.x;
    int q = t & 3;
    int sidx = t >> 2;
    int item = items[b];
    const uint4* irow = (const uint4*)(nodes_h + (size_t)item * DIM) + q * 4;
    uint4 a[4];
    #pragma unroll
    for (int c = 0; c < 4; ++c) a[c] = irow[c];

    int j = samples[b * SAMP + sidx];
    const uint4* srow = (const uint4*)(nodes_h + (size_t)j * DIM) + q * 4;
    uint4 s4[4];
    #pragma unroll
    for (int c = 0; c < 4; ++c) s4[c] = srow[c];

    float p = 0.f;
    #pragma unroll
    for (int c = 0; c < 4; ++c) {
        uint4 av = a[c], sv = s4[c];
        p += bl(av.x) * bl(sv.x) + bh(av.x) * bh(sv.x);
        p += bl(av.y) * bl(sv.y) + bh(av.y) * bh(sv.y);
        p += bl(av.z) * bl(sv.z) + bh(av.z) * bh(sv.z);
        p += bl(av.w) * bl(sv.w) + bh(av.w) * bh(sv.w);
    }
    p += __shfl_xor(p, 1, 64);
    p += __shfl_xor(p, 2, 64);
    if (q == 0) out[b * SAMP + sidx] = p;
}

extern "C" void kernel_launch(void* const* d_in, const int* in_sizes, int n_in,
                              void* d_out, int out_size, void* d_ws, size_t ws_size,
                              hipStream_t stream) {
    const int*   items   = (const int*)d_in[0];
    const int*   samples = (const int*)d_in[1];
    const int*   edges   = (const int*)d_in[2];
    const float* emb     = (const float*)d_in[3];
    const float* W       = (const float*)d_in[4];
    const float* bias    = (const float*)d_in[5];
    float* out = (float*)d_out;

    char* ws = (char*)d_ws;
    int*   cnt    = (int*)(ws + 0);                        // V ints (400 KB)
    int*   cursor = (int*)(ws + (512 << 10));              // V ints
    float* dinv   = (float*)(ws + (1 << 20));              // V floats
    int*   offs   = (int*)(ws + 3 * (512 << 10));          // V ints
    int*   bsum   = (int*)(ws + (2 << 20));                // 98 ints
    int*   boff   = (int*)(ws + (2 << 20) + (4 << 10));    // 98 ints
    unsigned short* wt_bf = (unsigned short*)(ws + (3 << 20));     // 128x128 bf16 (32 KB)
    int*   csr    = (int*)(ws + (4 << 20));                // E ints (2.56 MB)
    unsigned short* h_bf    = (unsigned short*)(ws + (8 << 20));   // V*DIM bf16 (25.6 MB)
    unsigned*       nodes_h = (unsigned*)(ws + (34 << 20));        // V*DIM bf16 (25.6 MB)

    const int* esrc = edges;
    const int* edst = edges + NEDGE;

    int nb = (V_NODES + 1023) / 1024;   // 98
    k_zero <<<98, 256, 0, stream>>>((int4*)cnt, V_NODES / 4);
    k_wcvt <<<16, 256, 0, stream>>>(W, wt_bf);
    // edge CSR: separate parallel kernels (fusion regressed: R9 coop, R11 scanoffs)
    k_count<<<(NEDGE + 255) / 256, 256, 0, stream>>>(edst, cnt, NEDGE);
    k_bsum <<<nb, 256, 0, stream>>>(cnt, bsum, V_NODES);
    k_bscan<<<1, 64, 0, stream>>>(bsum, boff, nb);
    k_offs <<<nb, 256, 0, stream>>>(cnt, boff, offs, dinv, cursor, V_NODES);
    k_fill <<<(NEDGE + 255) / 256, 256, 0, stream>>>(esrc, edst, cursor, csr, NEDGE);
    // GCN: MFMA GEMM first (reference order), then aggregate
    k_hgemm<<<(V_NODES + 127) / 128, 512, 0, stream>>>(emb, h_bf, wt_bf, V_NODES);
    k_agg  <<<(V_NODES + 7) / 8, 256, 0, stream>>>(h_bf, offs, cnt, csr, dinv, bias, nodes_h, V_NODES);
    // scoring
    k_score<<<BATCH, 256, 0, stream>>>((const unsigned short*)nodes_h, items, samples, out);
}

// Round 17
// 161.824 us; speedup vs baseline: 1.1686x; 1.0333x over previous
//
#include <hip/hip_runtime.h>
#include <hip/hip_bf16.h>

#define V_NODES 100000
#define DIM 128
#define BATCH 16384
#define SAMP 64
#define NEDGE 640000
#define NSAMP (BATCH * SAMP)
#define NB_CHUNK 98   // ceil(V/1024)

// bf16 helpers: raw-bit unpack (exact) and RNE pack
__device__ __forceinline__ float bl(unsigned u) { return __uint_as_float(u << 16); }
__device__ __forceinline__ float bh(unsigned u) { return __uint_as_float(u & 0xffff0000u); }
__device__ __forceinline__ unsigned short f2bf(float x) {
    unsigned u = __float_as_uint(x);
    return (unsigned short)((u + 0x7fffu + ((u >> 16) & 1u)) >> 16);
}

typedef __attribute__((ext_vector_type(8))) short bf16x8;
typedef __attribute__((ext_vector_type(4))) float f32x4;

// ---------- K0: merged init — blocks 0..97 zero cnt, blocks 98..113 W^T->bf16 ----------
__global__ void k_init(int4* __restrict__ cnt4, const float* __restrict__ W,
                       unsigned short* __restrict__ wt_bf) {
    int b = blockIdx.x;
    if (b < NB_CHUNK) {
        int i = b * 256 + threadIdx.x;
        if (i < V_NODES / 4) cnt4[i] = make_int4(0, 0, 0, 0);
    } else {
        int g = (b - NB_CHUNK) * 256 + threadIdx.x;   // 16 blocks x 256
        int n = g & 127;
        int k4 = (g >> 7) << 2;
        ushort4 o;
        o.x = f2bf(W[(k4 + 0) * 128 + n]);
        o.y = f2bf(W[(k4 + 1) * 128 + n]);
        o.z = f2bf(W[(k4 + 2) * 128 + n]);
        o.w = f2bf(W[(k4 + 3) * 128 + n]);
        *(ushort4*)(wt_bf + n * 128 + k4) = o;
    }
}

// ---------- K1: histogram of edge destinations (in-degree) ----------
__global__ void k_count(const int* __restrict__ key, int* __restrict__ cnt, int E) {
    int e = blockIdx.x * blockDim.x + threadIdx.x;
    if (e < E) atomicAdd(&cnt[key[e]], 1);
}

// ---------- K2a: per-1024-chunk sums ----------
__global__ void k_bsum(const int* __restrict__ cnt, int* __restrict__ bsum, int V) {
    __shared__ int red[4];
    int b = blockIdx.x, t = threadIdx.x;
    int s = 0;
    int base = b * 1024;
    for (int i = 0; i < 4; ++i) {
        int idx = base + i * 256 + t;
        if (idx < V) s += cnt[idx];
    }
    for (int m = 32; m >= 1; m >>= 1) s += __shfl_xor(s, m, 64);
    int lane = t & 63, wid = t >> 6;
    if (lane == 0) red[wid] = s;
    __syncthreads();
    if (t == 0) bsum[b] = red[0] + red[1] + red[2] + red[3];
}

// ---------- K2b: offsets + dinv + cursor; chunk prefix via in-block wave scan ----------
// wave 0 scans the 98 bsum values (2/lane) and picks this block's prefix —
// 98 L2-hot loads per block, removes the separate k_bscan kernel.
__global__ void k_offs(const int* __restrict__ cnt, const int* __restrict__ bsum,
                       int* __restrict__ offs, float* __restrict__ dinv,
                       int* __restrict__ cursor, int V) {
    __shared__ int wsum[4];
    __shared__ int s_boff;
    int b = blockIdx.x, t = threadIdx.x;
    int lane = t & 63, wid = t >> 6;
    if (wid == 0) {                       // inline scan of chunk sums
        int i0 = 2 * lane, i1 = 2 * lane + 1;
        int v0 = (i0 < NB_CHUNK) ? bsum[i0] : 0;
        int v1 = (i1 < NB_CHUNK) ? bsum[i1] : 0;
        int s = v0 + v1;
        int x = s;
        for (int off = 1; off < 64; off <<= 1) {
            int n = __shfl_up(x, off, 64);
            if (lane >= off) x += n;
        }
        int excl = x - s;
        if ((b >> 1) == lane) s_boff = (b & 1) ? (excl + v0) : excl;
    }
    int base = b * 1024 + t * 4;
    int c[4];
    for (int j = 0; j < 4; ++j) {
        int idx = base + j;
        c[j] = (idx < V) ? cnt[idx] : 0;
    }
    int tot = c[0] + c[1] + c[2] + c[3];
    int x = tot;
    for (int off = 1; off < 64; off <<= 1) {
        int n = __shfl_up(x, off, 64);
        if (lane >= off) x += n;
    }
    int lex = x - tot;
    if (lane == 63) wsum[wid] = x;
    __syncthreads();
    int wpre = 0;
    for (int w = 0; w < wid; ++w) wpre += wsum[w];
    int o = s_boff + wpre + lex;
    int pre = 0;
    for (int j = 0; j < 4; ++j) {
        int idx = base + j;
        if (idx < V) {
            int o0 = o + pre;
            offs[idx] = o0;
            cursor[idx] = o0;                        // absolute cursor
            dinv[idx] = 1.0f / sqrtf((float)(c[j] + 1));
        }
        pre += c[j];
    }
}

// ---------- K3: fill edge CSR (absolute atomic cursors) ----------
__global__ void k_fill(const int* __restrict__ src, const int* __restrict__ dst,
                       int* __restrict__ cursor, int* __restrict__ csr, int E) {
    int e = blockIdx.x * blockDim.x + threadIdx.x;
    if (e < E) {
        int pos = atomicAdd(&cursor[dst[e]], 1);
        csr[pos] = src[e];
    }
}

// ---------- K4: MFMA GEMM  h_bf = bf16(bf16(emb) @ bf16(W)) ----------
// 128 rows x 128 cols per block, 512 threads (8 waves x 16 rows). W^T staged
// once per block in a 32 KB XOR-swizzled LDS tile (conflicts=0, R16-proven).
// A direct from global (coalesced fp32, reg-cvt). Dead W tile reused for
// swizzled D staging.
__global__ __launch_bounds__(512) void k_hgemm(const float* __restrict__ emb,
                      unsigned short* __restrict__ h_bf,
                      const unsigned short* __restrict__ wt_bf, int V) {
    __shared__ unsigned short WtL[128 * 128];   // 32 KB
    int t = threadIdx.x;
    int rowbase = blockIdx.x * 128;
    for (int i = 0; i < 4; ++i) {
        int j = t + i * 512;
        int n = j >> 4, c8 = (j & 15) << 3;
        uint4 v = *(const uint4*)(wt_bf + n * 128 + c8);
        *(uint4*)&WtL[n * 128 + (c8 ^ ((n & 7) << 3))] = v;
    }
    int wid = t >> 6, lane = t & 63;   // 8 waves
    int r16  = lane & 15;
    int kgrp = lane >> 4;
    int grow = rowbase + wid * 16 + r16;
    const float* arow = emb + (size_t)grow * 128 + kgrp * 8;
    bool ok = (grow < V);
    float4 af[8];
    #pragma unroll
    for (int ks = 0; ks < 4; ++ks) {
        af[2 * ks]     = ok ? *(const float4*)(arow + ks * 32)     : make_float4(0.f, 0.f, 0.f, 0.f);
        af[2 * ks + 1] = ok ? *(const float4*)(arow + ks * 32 + 4) : make_float4(0.f, 0.f, 0.f, 0.f);
    }
    __syncthreads();
    f32x4 acc[8] = {};
    #pragma unroll
    for (int ks = 0; ks < 4; ++ks) {
        float4 a0 = af[2 * ks], a1 = af[2 * ks + 1];
        bf16x8 a;
        a[0] = (short)f2bf(a0.x); a[1] = (short)f2bf(a0.y);
        a[2] = (short)f2bf(a0.z); a[3] = (short)f2bf(a0.w);
        a[4] = (short)f2bf(a1.x); a[5] = (short)f2bf(a1.y);
        a[6] = (short)f2bf(a1.z); a[7] = (short)f2bf(a1.w);
        int kc = ks * 32 + kgrp * 8;
        #pragma unroll
        for (int n = 0; n < 8; ++n) {
            int wr = n * 16 + r16;
            bf16x8 b = *(const bf16x8*)&WtL[wr * 128 + (kc ^ ((wr & 7) << 3))];
            acc[n] = __builtin_amdgcn_mfma_f32_16x16x32_bf16(a, b, acc[n], 0, 0, 0);
        }
    }
    __syncthreads();   // WtL dead; reuse for D staging
    #pragma unroll
    for (int n = 0; n < 8; ++n) {
        #pragma unroll
        for (int r = 0; r < 4; ++r) {
            int drow = wid * 16 + kgrp * 4 + r;
            int dcol = n * 16 + r16;
            WtL[drow * 128 + (dcol ^ ((drow & 7) << 3))] = f2bf(acc[n][r]);
        }
    }
    __syncthreads();
    for (int i = 0; i < 4; ++i) {
        int j = t + i * 512;
        int r = j >> 4, c8 = (j & 15) << 3;
        uint4 v = *(const uint4*)&WtL[r * 128 + (c8 ^ ((r & 7) << 3))];
        int gr = rowbase + r;
        if (gr < V) *(uint4*)(h_bf + (size_t)gr * 128 + c8) = v;
    }
}

// ---------- K5: aggregate h, + bias, write bf16 nodes ----------
// TWO nodes per wave, interleaved x2 -> 4 independent gathers in flight.
__global__ __launch_bounds__(256) void k_agg(const unsigned short* __restrict__ h_bf,
                     const int* __restrict__ offs, const int* __restrict__ cnt,
                     const int* __restrict__ csr, const float* __restrict__ dinv,
                     const float* __restrict__ bias,
                     unsigned* __restrict__ nodes_h, int V) {
    int wv = threadIdx.x >> 6;
    int lane = threadIdx.x & 63;
    int vA = blockIdx.x * 8 + wv * 2;
    int vB = vA + 1;
    if (vA >= V) return;
    bool hasB = (vB < V);
    float dvA = dinv[vA];
    float dvB = hasB ? dinv[vB] : 0.f;
    int begA = offs[vA], numA = cnt[vA];
    int begB = hasB ? offs[vB] : 0, numB = hasB ? cnt[vB] : 0;
    int nidA = 0, nidB = 0; float nwA = 0.f, nwB = 0.f;
    if (lane < numA) { nidA = csr[begA + lane]; nwA = dinv[nidA]; }
    if (lane < numB) { nidB = csr[begB + lane]; nwB = dinv[nidB]; }
    unsigned u0A = ((const unsigned*)(h_bf + (size_t)vA * DIM))[lane];
    unsigned u0B = hasB ? ((const unsigned*)(h_bf + (size_t)vB * DIM))[lane] : 0u;
    float2 bv = ((const float2*)bias)[lane];
    float axA = bv.x + dvA * dvA * bl(u0A), ayA = bv.y + dvA * dvA * bh(u0A);
    float axB = bv.x + dvB * dvB * bl(u0B), ayB = bv.y + dvB * dvB * bh(u0B);
    float cxA = 0.f, cyA = 0.f, cxB = 0.f, cyB = 0.f;
    int nA = min(numA, 64), nB = min(numB, 64);
    int m = min(nA, nB);
    int i = 0;
    for (; i + 2 <= m; i += 2) {            // interleaved: 4 loads in flight
        int sA0 = __shfl(nidA, i, 64),     sB0 = __shfl(nidB, i, 64);
        int sA1 = __shfl(nidA, i + 1, 64), sB1 = __shfl(nidB, i + 1, 64);
        float wA0 = dvA * __shfl(nwA, i, 64),     wB0 = dvB * __shfl(nwB, i, 64);
        float wA1 = dvA * __shfl(nwA, i + 1, 64), wB1 = dvB * __shfl(nwB, i + 1, 64);
        unsigned eA0 = ((const unsigned*)(h_bf + (size_t)sA0 * DIM))[lane];
        unsigned eB0 = ((const unsigned*)(h_bf + (size_t)sB0 * DIM))[lane];
        unsigned eA1 = ((const unsigned*)(h_bf + (size_t)sA1 * DIM))[lane];
        unsigned eB1 = ((const unsigned*)(h_bf + (size_t)sB1 * DIM))[lane];
        axA += wA0 * bl(eA0); ayA += wA0 * bh(eA0);
        axB += wB0 * bl(eB0); ayB += wB0 * bh(eB0);
        cxA += wA1 * bl(eA1); cyA += wA1 * bh(eA1);
        cxB += wB1 * bl(eB1); cyB += wB1 * bh(eB1);
    }
    int ia = i;
    for (; ia + 2 <= nA; ia += 2) {
        int s0 = __shfl(nidA, ia, 64), s1 = __shfl(nidA, ia + 1, 64);
        float w0 = dvA * __shfl(nwA, ia, 64), w1 = dvA * __shfl(nwA, ia + 1, 64);
        unsigned e0 = ((const unsigned*)(h_bf + (size_t)s0 * DIM))[lane];
        unsigned e1 = ((const unsigned*)(h_bf + (size_t)s1 * DIM))[lane];
        axA += w0 * bl(e0); ayA += w0 * bh(e0);
        cxA += w1 * bl(e1); cyA += w1 * bh(e1);
    }
    for (; ia < nA; ++ia) {
        int s = __shfl(nidA, ia, 64);
        float w = dvA * __shfl(nwA, ia, 64);
        unsigned u = ((const unsigned*)(h_bf + (size_t)s * DIM))[lane];
        axA += w * bl(u); ayA += w * bh(u);
    }
    int ib = i;
    for (; ib + 2 <= nB; ib += 2) {
        int s0 = __shfl(nidB, ib, 64), s1 = __shfl(nidB, ib + 1, 64);
        float w0 = dvB * __shfl(nwB, ib, 64), w1 = dvB * __shfl(nwB, ib + 1, 64);
        unsigned e0 = ((const unsigned*)(h_bf + (size_t)s0 * DIM))[lane];
        unsigned e1 = ((const unsigned*)(h_bf + (size_t)s1 * DIM))[lane];
        axB += w0 * bl(e0); ayB += w0 * bh(e0);
        cxB += w1 * bl(e1); cyB += w1 * bh(e1);
    }
    for (; ib < nB; ++ib) {
        int s = __shfl(nidB, ib, 64);
        float w = dvB * __shfl(nwB, ib, 64);
        unsigned u = ((const unsigned*)(h_bf + (size_t)s * DIM))[lane];
        axB += w * bl(u); ayB += w * bh(u);
    }
    for (int k = 64; k < numA; ++k) {       // cold fallback deg>64
        int s = csr[begA + k];
        float w = dvA * dinv[s];
        unsigned u = ((const unsigned*)(h_bf + (size_t)s * DIM))[lane];
        axA += w * bl(u); ayA += w * bh(u);
    }
    for (int k = 64; k < numB; ++k) {
        int s = csr[begB + k];
        float w = dvB * dinv[s];
        unsigned u = ((const unsigned*)(h_bf + (size_t)s * DIM))[lane];
        axB += w * bl(u); ayB += w * bh(u);
    }
    axA += cxA; ayA += cyA;
    nodes_h[(size_t)vA * (DIM / 2) + lane] =
        (unsigned)f2bf(axA) | ((unsigned)f2bf(ayA) << 16);
    if (hasB) {
        axB += cxB; ayB += cyB;
        nodes_h[(size_t)vB * (DIM / 2) + lane] =
            (unsigned)f2bf(axB) | ((unsigned)f2bf(ayB) << 16);
    }
}

// ---------- K6: scores[b,s] = dot(nodes[items[b]], nodes[samples[b,s]]) ----------
// R7 shape (best measured): 256-thread block per item; 4 threads per sample.
__global__ __launch_bounds__(256) void k_score(const unsigned short* __restrict__ nodes_h,
                      const int* __restrict__ items, const int* __restrict__ samples,
                      float* __restrict__ out) {
    int b = blockIdx.x;
    int t = threadIdx.x;
    int q = t & 3;
    int sidx = t >> 2;
    int item = items[b];
    const uint4* irow = (const uint4*)(nodes_h + (size_t)item * DIM) + q * 4;
    uint4 a[4];
    #pragma unroll
    for (int c = 0; c < 4; ++c) a[c] = irow[c];

    int j = samples[b * SAMP + sidx];
    const uint4* srow = (const uint4*)(nodes_h + (size_t)j * DIM) + q * 4;
    uint4 s4[4];
    #pragma unroll
    for (int c = 0; c < 4; ++c) s4[c] = srow[c];

    float p = 0.f;
    #pragma unroll
    for (int c = 0; c < 4; ++c) {
        uint4 av = a[c], sv = s4[c];
        p += bl(av.x) * bl(sv.x) + bh(av.x) * bh(sv.x);
        p += bl(av.y) * bl(sv.y) + bh(av.y) * bh(sv.y);
        p += bl(av.z) * bl(sv.z) + bh(av.z) * bh(sv.z);
        p += bl(av.w) * bl(sv.w) + bh(av.w) * bh(sv.w);
    }
    p += __shfl_xor(p, 1, 64);
    p += __shfl_xor(p, 2, 64);
    if (q == 0) out[b * SAMP + sidx] = p;
}

extern "C" void kernel_launch(void* const* d_in, const int* in_sizes, int n_in,
                              void* d_out, int out_size, void* d_ws, size_t ws_size,
                              hipStream_t stream) {
    const int*   items   = (const int*)d_in[0];
    const int*   samples = (const int*)d_in[1];
    const int*   edges   = (const int*)d_in[2];
    const float* emb     = (const float*)d_in[3];
    const float* W       = (const float*)d_in[4];
    const float* bias    = (const float*)d_in[5];
    float* out = (float*)d_out;

    char* ws = (char*)d_ws;
    int*   cnt    = (int*)(ws + 0);                        // V ints (400 KB)
    int*   cursor = (int*)(ws + (512 << 10));              // V ints
    float* dinv   = (float*)(ws + (1 << 20));              // V floats
    int*   offs   = (int*)(ws + 3 * (512 << 10));          // V ints
    int*   bsum   = (int*)(ws + (2 << 20));                // 98 ints
    unsigned short* wt_bf = (unsigned short*)(ws + (3 << 20));     // 128x128 bf16 (32 KB)
    int*   csr    = (int*)(ws + (4 << 20));                // E ints (2.56 MB)
    unsigned short* h_bf    = (unsigned short*)(ws + (8 << 20));   // V*DIM bf16 (25.6 MB)
    unsigned*       nodes_h = (unsigned*)(ws + (34 << 20));        // V*DIM bf16 (25.6 MB)

    const int* esrc = edges;
    const int* edst = edges + NEDGE;

    // 8 dispatches total (was 10): init merges zero+wcvt; bscan folded into offs
    k_init <<<NB_CHUNK + 16, 256, 0, stream>>>((int4*)cnt, W, wt_bf);
    k_count<<<(NEDGE + 255) / 256, 256, 0, stream>>>(edst, cnt, NEDGE);
    k_bsum <<<NB_CHUNK, 256, 0, stream>>>(cnt, bsum, V_NODES);
    k_offs <<<NB_CHUNK, 256, 0, stream>>>(cnt, bsum, offs, dinv, cursor, V_NODES);
    k_fill <<<(NEDGE + 255) / 256, 256, 0, stream>>>(esrc, edst, cursor, csr, NEDGE);
    // GCN: MFMA GEMM first (reference order), then aggregate
    k_hgemm<<<(V_NODES + 127) / 128, 512, 0, stream>>>(emb, h_bf, wt_bf, V_NODES);
    k_agg  <<<(V_NODES + 7) / 8, 256, 0, stream>>>(h_bf, offs, cnt, csr, dinv, bias, nodes_h, V_NODES);
    // scoring
    k_score<<<BATCH, 256, 0, stream>>>((const unsigned short*)nodes_h, items, samples, out);
}